// Round 2
// baseline (340.166 us; speedup 1.0000x reference)
//
#include <hip/hip_runtime.h>
#include <stdint.h>

#define S 64
#define NSQ 32
#define Lc 2048
#define Cc 512
#define Ec 128
#define OUT_H (S*NSQ*Lc)   /* 4194304 */

typedef __bf16 bf16x8 __attribute__((ext_vector_type(8)));
typedef float floatx4 __attribute__((ext_vector_type(4)));

__device__ __forceinline__ unsigned short f2bf(float f){
  union { float f; uint32_t u; } v; v.f = f;
  uint32_t r = v.u + 0x7fffu + ((v.u >> 16) & 1u);
  return (unsigned short)(r >> 16);
}

// ---------------------------------------------------------------------------
// k_prep: dynamic weights w[s][c][k], b[s][c]; W1->bf16; W2 rearrange->bf16;
// zero logdet; copy h1 -> out.   grid 512 x 256  (full batch, tiny buffers)
// ---------------------------------------------------------------------------
__global__ void k_prep(const float* __restrict__ h, const float* __restrict__ emb,
                       const float* __restrict__ Wa, const float* __restrict__ ba,
                       const float* __restrict__ Wb, const float* __restrict__ bb,
                       const float* __restrict__ W1, const float* __restrict__ W2,
                       float* __restrict__ dynW, float* __restrict__ dynB,
                       unsigned short* __restrict__ W1bf, unsigned short* __restrict__ W2bf,
                       float* __restrict__ out)
{
  __shared__ float embl[Ec];
  int tid = threadIdx.x;
  int b = blockIdx.x;          // 512 blocks, 8 per sample
  int s = b >> 3;
  int o = ((b & 7) << 8) | tid;   // 0..2047 (1536 dynW dots + 512 dynB dots)
  if (tid < Ec) embl[tid] = emb[s*Ec + tid];
  __syncthreads();
  const float* row; float bias; float* dst;
  if (o < 1536) { row = Wa + o*Ec; bias = ba[o]; dst = dynW + s*1536 + o; }
  else { int c = o - 1536; row = Wb + c*Ec; bias = bb[c]; dst = dynB + s*Cc + c; }
  float acc = bias;
  const float4* r4 = (const float4*)row;
  #pragma unroll 8
  for (int e = 0; e < Ec/4; e++) {
    float4 rv = r4[e];
    acc += embl[4*e]*rv.x + embl[4*e+1]*rv.y + embl[4*e+2]*rv.z + embl[4*e+3]*rv.w;
  }
  *dst = acc;

  int gtid = b*256 + tid;      // 0..131071
  // W1 convert: 262144 elems, 2/thread. W1 is [o][c][1] row-major == [o][c].
  {
    float2 wv = ((const float2*)W1)[gtid];
    W1bf[2*gtid]   = f2bf(wv.x);
    W1bf[2*gtid+1] = f2bf(wv.y);
  }
  // W2 rearrange: dst [k][j][c] <- src [j][c][k]  (49152 elems)
  if (gtid < 3*32*Cc) {
    int k = gtid >> 14;
    int rem = gtid & 16383;
    int j = rem >> 9, c = rem & 511;
    W2bf[gtid] = f2bf(W2[j*1536 + c*3 + k]);
  }
  if (gtid < S) out[OUT_H + gtid] = 0.f;   // logdet accumulators
  // h1 copy: first 16 rows of each sample (8192 float4/sample), 4/thread
  {
    const float4* hs = (const float4*)h;
    float4* od = (float4*)out;
    #pragma unroll
    for (int i = 0; i < 4; i++) {
      int v = gtid + i*131072;      // 0..524287
      int ss = v >> 13;             // v / 8192
      int r = v & 8191;
      od[ss*16384 + r] = hs[ss*16384 + r];
    }
  }
}

// ---------------------------------------------------------------------------
// k_x: X[sl*L + l][c] = bf16(relu(sum_k w[s,c,k]*h1[s,c>>5,l+k-1] + b[s,c]))
// sl = local sample (chunk), s = s0 + sl. grid 128*SC x 256
// ---------------------------------------------------------------------------
__global__ void k_x(const float* __restrict__ h,
                    const float* __restrict__ dynW, const float* __restrict__ dynB,
                    unsigned short* __restrict__ X, int s0)
{
  int gtid = blockIdx.x*256 + threadIdx.x;
  int c4 = gtid & 127;
  int lg = (gtid >> 7) & 255;
  int sl = gtid >> 15;
  int s  = s0 + sl;
  int c  = c4 << 2;
  int l0 = lg << 3;
  int q  = c >> 5;
  const float4* wp = (const float4*)(dynW + s*1536 + c*3);
  float4 w0 = wp[0], w1 = wp[1], w2 = wp[2];
  float wt[4][3] = {{w0.x,w0.y,w0.z},{w0.w,w1.x,w1.y},{w1.z,w1.w,w2.x},{w2.y,w2.z,w2.w}};
  float4 bs = *(const float4*)(dynB + s*Cc + c);
  float bv[4] = {bs.x, bs.y, bs.z, bs.w};
  const float* row = h + s*(NSQ*Lc) + q*Lc;
  float hm = (l0 > 0) ? row[l0-1] : 0.f;
  float hc = row[l0];
  unsigned short* Xp = X + (size_t)(sl*Lc + l0)*Cc + c;
  #pragma unroll
  for (int i = 0; i < 8; i++) {
    int l = l0 + i;
    float hp = (l+1 < Lc) ? row[l+1] : 0.f;
    float v0 = fmaxf(wt[0][0]*hm + wt[0][1]*hc + wt[0][2]*hp + bv[0], 0.f);
    float v1 = fmaxf(wt[1][0]*hm + wt[1][1]*hc + wt[1][2]*hp + bv[1], 0.f);
    float v2 = fmaxf(wt[2][0]*hm + wt[2][1]*hc + wt[2][2]*hp + bv[2], 0.f);
    float v3 = fmaxf(wt[3][0]*hm + wt[3][1]*hc + wt[3][2]*hp + bv[3], 0.f);
    ushort4 st;
    st.x = f2bf(v0); st.y = f2bf(v1); st.z = f2bf(v2); st.w = f2bf(v3);
    *(ushort4*)(Xp) = st;
    Xp += Cc;
    hm = hc; hc = hp;
  }
}

// ---------------------------------------------------------------------------
// k_gemm1: X2[n][o] = bf16(relu(sum_c W1[o][c]*X[n][c] + b1[o]))
// M=512 (grid.y=4 x 128), N=SC*2048 (grid.x=SC*16 x 128), K=512 (BK=64).
// 4 waves (2x2), wave tile 64x64 (4x4 frags of 16x16x32 bf16).
// ---------------------------------------------------------------------------
__global__ void __launch_bounds__(256) k_gemm1(
    const unsigned short* __restrict__ W1bf, const unsigned short* __restrict__ X,
    const float* __restrict__ b1, unsigned short* __restrict__ X2)
{
  __shared__ unsigned short As[128*72];
  __shared__ unsigned short Bs[128*72];
  int tid = threadIdx.x;
  int nb = blockIdx.x;
  int mb = blockIdx.y;   // 0..3
  int wid = tid >> 6, ln16 = tid & 15, quad = (tid & 63) >> 4;
  int wm = wid & 1, wn = wid >> 1;
  floatx4 acc[4][4];
  #pragma unroll
  for (int mi = 0; mi < 4; mi++)
    #pragma unroll
    for (int ni = 0; ni < 4; ni++)
      acc[mi][ni] = (floatx4){0.f,0.f,0.f,0.f};

  for (int c0 = 0; c0 < 512; c0 += 64) {
    __syncthreads();
    #pragma unroll
    for (int j = 0; j < 4; j++) {
      int chunk = tid + j*256;          // 128 rows x 8 16B-chunks
      int row = chunk >> 3, c16 = chunk & 7;
      *(uint4*)&As[row*72 + c16*8] = *(const uint4*)&W1bf[(mb*128 + row)*512 + c0 + c16*8];
      *(uint4*)&Bs[row*72 + c16*8] = *(const uint4*)&X[(size_t)(nb*128 + row)*512 + c0 + c16*8];
    }
    __syncthreads();
    #pragma unroll
    for (int kk = 0; kk < 64; kk += 32) {
      bf16x8 af[4], bfr[4];
      #pragma unroll
      for (int mi = 0; mi < 4; mi++)
        af[mi] = *(const bf16x8*)&As[(wm*64 + mi*16 + ln16)*72 + kk + quad*8];
      #pragma unroll
      for (int ni = 0; ni < 4; ni++)
        bfr[ni] = *(const bf16x8*)&Bs[(wn*64 + ni*16 + ln16)*72 + kk + quad*8];
      #pragma unroll
      for (int mi = 0; mi < 4; mi++)
        #pragma unroll
        for (int ni = 0; ni < 4; ni++)
          acc[mi][ni] = __builtin_amdgcn_mfma_f32_16x16x32_bf16(af[mi], bfr[ni], acc[mi][ni], 0, 0, 0);
    }
  }
  // epilogue: +b1, relu, bf16, store [n][o] (reg quad = 4 consecutive o)
  #pragma unroll
  for (int mi = 0; mi < 4; mi++) {
    int ob = mb*128 + wm*64 + mi*16 + quad*4;
    float4 bb4 = *(const float4*)(b1 + ob);
    #pragma unroll
    for (int ni = 0; ni < 4; ni++) {
      int n = nb*128 + wn*64 + ni*16 + ln16;
      ushort4 st;
      st.x = f2bf(fmaxf(acc[mi][ni][0] + bb4.x, 0.f));
      st.y = f2bf(fmaxf(acc[mi][ni][1] + bb4.y, 0.f));
      st.z = f2bf(fmaxf(acc[mi][ni][2] + bb4.z, 0.f));
      st.w = f2bf(fmaxf(acc[mi][ni][3] + bb4.w, 0.f));
      *(ushort4*)&X2[(size_t)n*512 + ob] = st;
    }
  }
}

// ---------------------------------------------------------------------------
// k_out: x3[j][l] = sum_{k,c} W2r[k][j][c] * X2[l+k-1][c] + b2[j]
// then s=sigmoid(x3[:16]+2)+1e-7, m=x3[16:], out h2' = s*(h2+m), logdet.
// grid (32, SC): block per (sl, 64-wide l tile). s = s0 + sl.
// ---------------------------------------------------------------------------
__global__ void __launch_bounds__(256) k_out(
    const unsigned short* __restrict__ X2, const unsigned short* __restrict__ W2bf,
    const float* __restrict__ b2, const float* __restrict__ h,
    float* __restrict__ out, int s0)
{
  extern __shared__ char smem[];
  unsigned short* x2t = (unsigned short*)smem;          // [66][520] bf16
  float* x3b = (float*)(smem + 66*520*2);               // [64][36] f32
  float* red = (float*)(smem + 66*520*2 + 64*36*4);     // [4]
  int tid = threadIdx.x;
  int tile = blockIdx.x;   // 0..31
  int sl = blockIdx.y;
  int s = s0 + sl;
  int l0 = tile*64;
  // stage X2 tile rows l0-1 .. l0+64 (zero-padded at edges)
  for (int chunk = tid; chunk < 66*64; chunk += 256) {
    int lr = chunk >> 6, c8 = chunk & 63;
    int l = l0 - 1 + lr;
    uint4 v = {0u,0u,0u,0u};
    if (l >= 0 && l < Lc) v = *(const uint4*)&X2[(size_t)(sl*Lc + l)*Cc + c8*8];
    *(uint4*)&x2t[lr*520 + c8*8] = v;
  }
  __syncthreads();
  int wid = tid >> 6, ln16 = tid & 15, quad = (tid & 63) >> 4;
  int jh = wid & 1, nh = wid >> 1;
  floatx4 acc[2];
  acc[0] = (floatx4){0.f,0.f,0.f,0.f};
  acc[1] = (floatx4){0.f,0.f,0.f,0.f};
  #pragma unroll
  for (int k = 0; k < 3; k++) {
    for (int c0 = 0; c0 < 512; c0 += 32) {
      bf16x8 af = *(const bf16x8*)&W2bf[k*16384 + (jh*16 + ln16)*512 + c0 + quad*8];
      #pragma unroll
      for (int ni = 0; ni < 2; ni++) {
        bf16x8 bfr = *(const bf16x8*)&x2t[(nh*32 + ni*16 + ln16 + k)*520 + c0 + quad*8];
        acc[ni] = __builtin_amdgcn_mfma_f32_16x16x32_bf16(af, bfr, acc[ni], 0, 0, 0);
      }
    }
  }
  // +b2, park x3 in LDS to pair (s-half, m-half) across waves
  float4 b2v = *(const float4*)(b2 + jh*16 + quad*4);
  #pragma unroll
  for (int ni = 0; ni < 2; ni++) {
    int lloc = nh*32 + ni*16 + ln16;
    float4 st;
    st.x = acc[ni][0] + b2v.x;
    st.y = acc[ni][1] + b2v.y;
    st.z = acc[ni][2] + b2v.z;
    st.w = acc[ni][3] + b2v.w;
    *(float4*)&x3b[lloc*36 + jh*16 + quad*4] = st;
  }
  __syncthreads();
  float ld = 0.f;
  #pragma unroll
  for (int it = 0; it < 4; it++) {
    int idx = it*256 + tid;        // 0..1023 -> (q 0..15, lloc 0..63)
    int lloc = idx & 63, q = idx >> 6;
    float sv = 1.f / (1.f + __expf(-(x3b[lloc*36 + q] + 2.f))) + 1e-7f;
    float mv = x3b[lloc*36 + q + 16];
    int gi = s*(NSQ*Lc) + (16+q)*Lc + l0 + lloc;
    out[gi] = sv * (h[gi] + mv);
    ld += __logf(sv);
  }
  #pragma unroll
  for (int off = 32; off > 0; off >>= 1) ld += __shfl_down(ld, off);
  if ((tid & 63) == 0) red[wid] = ld;
  __syncthreads();
  if (tid == 0) atomicAdd(&out[OUT_H + s], red[0]+red[1]+red[2]+red[3]);
}

// ---------------------------------------------------------------------------
extern "C" void kernel_launch(void* const* d_in, const int* in_sizes, int n_in,
                              void* d_out, int out_size, void* d_ws, size_t ws_size,
                              hipStream_t stream) {
  const float* h   = (const float*)d_in[0];
  const float* emb = (const float*)d_in[1];
  const float* Wa  = (const float*)d_in[2];
  const float* ba  = (const float*)d_in[3];
  const float* Wb  = (const float*)d_in[4];
  const float* bb  = (const float*)d_in[5];
  const float* W1  = (const float*)d_in[6];
  const float* b1  = (const float*)d_in[7];
  const float* W2  = (const float*)d_in[8];
  const float* b2  = (const float*)d_in[9];
  float* out = (float*)d_out;
  char* ws = (char*)d_ws;

  const size_t prefix = 1179648;   // dynW 384K + dynB 128K + W1bf 512K + W2bf 96K (+pad)
  float* dynW = (float*)(ws + 0);
  float* dynB = (float*)(ws + 393216);
  unsigned short* W1bf = (unsigned short*)(ws + 524288);
  unsigned short* W2bf = (unsigned short*)(ws + 1048576);

  // Adaptive chunking over the batch: per-sample scratch = 2 x 2 MiB (X, X2).
  int SC = 0;
  for (int cand = 64; cand >= 1; cand >>= 1) {
    if (prefix + (size_t)cand * 4194304ull <= ws_size) { SC = cand; break; }
  }
  if (SC == 0) return;  // ws too small even for 1 sample (~5.4 MB)

  unsigned short* X  = (unsigned short*)(ws + prefix);
  unsigned short* X2 = (unsigned short*)(ws + prefix + (size_t)SC * 2097152ull);

  k_prep<<<512, 256, 0, stream>>>(h, emb, Wa, ba, Wb, bb, W1, W2,
                                  dynW, dynB, W1bf, W2bf, out);
  for (int s0 = 0; s0 < S; s0 += SC) {
    k_x<<<128*SC, 256, 0, stream>>>(h, dynW, dynB, X, s0);
    k_gemm1<<<dim3(16*SC, 4), 256, 0, stream>>>(W1bf, X, b1, X2);
    k_out<<<dim3(32, SC), 256, 66*520*2 + 64*36*4 + 16, stream>>>(X2, W2bf, b2, h, out, s0);
  }
}